// Round 1
// baseline (955.299 us; speedup 1.0000x reference)
//
#include <hip/hip_runtime.h>
#include <hip/hip_bf16.h>

#define T_TOK 8192
#define E_EXP 8
#define DDIM  768
#define FDIM  3072

typedef _Float16 f16x8 __attribute__((ext_vector_type(8)));
typedef _Float16 f16x4 __attribute__((ext_vector_type(4)));
typedef float    f32x4 __attribute__((ext_vector_type(4)));

// ---------------- workspace layout (bytes, all 256-aligned) ----------------
static const size_t XH_OFF   = 0;                         // 8192*768*2   = 12,582,912
static const size_t W1H_OFF  = 12582912;                  // 8*3072*768*2 = 37,748,736
static const size_t W2H_OFF  = 50331648;                  // 37,748,736
static const size_t WS1H_OFF = 88080384;                  // 4,718,592
static const size_t WS2H_OFF = 92798976;                  // 4,718,592
static const size_t H_OFF    = 97517568;                  // 16384*3072*2 = 100,663,296
static const size_t ROWS_OFF = 198180864;                 // 65,536
static const size_t RW_OFF   = 198246400;                 // 65,536
static const size_t TIDX_OFF = 198311936;                 // 65,536
static const size_t TW_OFF   = 198377472;                 // 65,536
static const size_t CNT_OFF  = 198443008;                 // 256
static const size_t BASE_OFF = 198443264;                 // 256
static const size_t CUR_OFF  = 198443520;                 // 256
static const size_t WS_NEED  = 198443776;

// ---------------- fp32 -> fp16 convert (vectorized) ----------------
__global__ void cvt_f32_f16(const float* __restrict__ src, _Float16* __restrict__ dst, int n4) {
    int i = blockIdx.x * blockDim.x + threadIdx.x;
    if (i >= n4) return;
    float4 v = ((const float4*)src)[i];
    f16x4 o = { (_Float16)v.x, (_Float16)v.y, (_Float16)v.z, (_Float16)v.w };
    *(f16x4*)(dst + 4 * (size_t)i) = o;
}

// ---------------- gate: fp32 logits, top-2, renormalized weights ----------------
__global__ void gate_kernel(const float* __restrict__ x, const float* __restrict__ gw,
                            int* __restrict__ tidx, float* __restrict__ tw,
                            int* __restrict__ cnt) {
    int wave = threadIdx.x >> 6;
    int lane = threadIdx.x & 63;
    int t = blockIdx.x * 4 + wave;
    const float4* xv = (const float4*)(x + (size_t)t * DDIM);
    float p[E_EXP];
#pragma unroll
    for (int e = 0; e < E_EXP; e++) p[e] = 0.f;
    for (int i = lane; i < DDIM / 4; i += 64) {
        float4 xv4 = xv[i];
#pragma unroll
        for (int e = 0; e < E_EXP; e++) {
            float4 g = ((const float4*)(gw + (size_t)e * DDIM))[i];
            p[e] += xv4.x * g.x + xv4.y * g.y + xv4.z * g.z + xv4.w * g.w;
        }
    }
#pragma unroll
    for (int e = 0; e < E_EXP; e++) {
#pragma unroll
        for (int off = 32; off; off >>= 1) p[e] += __shfl_xor(p[e], off);
    }
    if (lane == 0) {
        int i0 = 0;
#pragma unroll
        for (int e = 1; e < E_EXP; e++) if (p[e] > p[i0]) i0 = e;
        int i1 = (i0 == 0) ? 1 : 0;
#pragma unroll
        for (int e = 0; e < E_EXP; e++) {
            if (e == i0) continue;
            if (p[e] > p[i1]) i1 = e;
        }
        // renormalized top-2 softmax depends only on the two logits
        float d  = p[i1] - p[i0];          // <= 0
        float e1 = expf(d);
        float w0 = 1.f / (1.f + e1);
        float w1 = 1.f - w0;
        tidx[2 * t]     = i0;  tw[2 * t]     = w0;
        tidx[2 * t + 1] = i1;  tw[2 * t + 1] = w1;
        atomicAdd(&cnt[i0], 1);
        atomicAdd(&cnt[i1], 1);
    }
}

__global__ void offsets_kernel(const int* __restrict__ cnt, int* __restrict__ base,
                               int* __restrict__ cur) {
    if (threadIdx.x == 0 && blockIdx.x == 0) {
        int acc = 0;
        for (int e = 0; e < E_EXP; e++) { base[e] = acc; cur[e] = acc; acc += cnt[e]; }
    }
}

__global__ void scatter_kernel(const int* __restrict__ tidx, const float* __restrict__ tw,
                               int* __restrict__ cur, int* __restrict__ rowsIdx,
                               float* __restrict__ rw) {
    int t = blockIdx.x * blockDim.x + threadIdx.x;
    if (t >= T_TOK) return;
#pragma unroll
    for (int k = 0; k < 2; k++) {
        int e = tidx[2 * t + k];
        int slot = atomicAdd(&cur[e], 1);
        rowsIdx[slot] = t;
        rw[slot] = tw[2 * t + k];
    }
}

// ---------------- MFMA GEMM, 128x128 tile, BK=64, 4 waves ----------------
// Modes: 0=FC1 shared  1=FC2 shared  2=FC1 routed  3=FC2 routed
#define FC1S 0
#define FC2S 1
#define FC1R 2
#define FC2R 3

template <int MODE>
__global__ __launch_bounds__(256, 2) void gemm_kernel(
    const _Float16* __restrict__ Abase,   // xh (fc1) or h (fc2), lda == K
    const _Float16* __restrict__ Wbase,   // [N,K] row-major (per expert for routed)
    const float* __restrict__ biasBase,
    _Float16* __restrict__ h,             // fc1 output
    float* __restrict__ out,              // fc2 output
    const int* __restrict__ cnt, const int* __restrict__ base,
    const int* __restrict__ rowsIdx, const float* __restrict__ rw)
{
    constexpr int K = (MODE == FC1S || MODE == FC1R) ? DDIM : FDIM;
    constexpr int N = (MODE == FC1S || MODE == FC1R) ? FDIM : DDIM;
    constexpr bool ROUTED = (MODE == FC1R || MODE == FC2R);

    int m0, mEnd;
    const _Float16* W;
    const float* bias;
    if constexpr (ROUTED) {
        int bx = blockIdx.x, accb = 0, expert = -1, rb = 0;
#pragma unroll
        for (int e = 0; e < E_EXP; e++) {
            int nb = (cnt[e] + 127) >> 7;
            if (expert < 0 && bx < accb + nb) { expert = e; rb = bx - accb; }
            accb += nb;
        }
        if (expert < 0) return;
        m0   = base[expert] + rb * 128;
        mEnd = base[expert] + cnt[expert];
        W    = Wbase + (size_t)expert * N * K;
        bias = biasBase + (size_t)expert * N;
    } else {
        m0 = blockIdx.x * 128;
        mEnd = T_TOK;
        W = Wbase;
        bias = biasBase;
    }
    int n0 = blockIdx.y * 128;

    __shared__ __align__(16) _Float16 As[128 * 72];   // stride 72 elems = 144B: 16B-aligned, 2-way bank alias (free)
    __shared__ __align__(16) _Float16 Bs[128 * 72];

    int tid  = threadIdx.x;
    int lane = tid & 63;
    int wid  = tid >> 6;
    int wm   = wid >> 1, wn = wid & 1;
    int m16  = lane & 15, q = lane >> 4;

    f32x4 acc[4][4];
#pragma unroll
    for (int i = 0; i < 4; i++)
#pragma unroll
        for (int j = 0; j < 4; j++) acc[i][j] = f32x4{0.f, 0.f, 0.f, 0.f};

    // A-row indices for this thread's 4 staging segments (fixed across K)
    int arowg[4];
#pragma unroll
    for (int tse = 0; tse < 4; tse++) {
        int s = tid + tse * 256;
        int row = s >> 3;
        int pr = m0 + row;
        bool valid = pr < mEnd;
        int ar;
        if constexpr (MODE == FC1R) ar = valid ? rowsIdx[pr] : 0;
        else                        ar = pr;
        arowg[tse] = valid ? ar : -1;
    }

    for (int k0 = 0; k0 < K; k0 += 64) {
#pragma unroll
        for (int tse = 0; tse < 4; tse++) {
            int s = tid + tse * 256;
            int row = s >> 3, cs = s & 7;
            int4 v = make_int4(0, 0, 0, 0);
            int ar = arowg[tse];
            if (ar >= 0) v = *(const int4*)(Abase + (size_t)ar * K + k0 + cs * 8);
            *(int4*)(As + row * 72 + cs * 8) = v;
        }
#pragma unroll
        for (int tse = 0; tse < 4; tse++) {
            int s = tid + tse * 256;
            int row = s >> 3, cs = s & 7;
            int4 v = *(const int4*)(W + (size_t)(n0 + row) * K + k0 + cs * 8);
            *(int4*)(Bs + row * 72 + cs * 8) = v;
        }
        __syncthreads();
#pragma unroll
        for (int ks = 0; ks < 2; ks++) {
            f16x8 af[4], bf[4];
#pragma unroll
            for (int i = 0; i < 4; i++)
                af[i] = *(const f16x8*)(As + (wm * 64 + i * 16 + m16) * 72 + ks * 32 + q * 8);
#pragma unroll
            for (int j = 0; j < 4; j++)
                bf[j] = *(const f16x8*)(Bs + (wn * 64 + j * 16 + m16) * 72 + ks * 32 + q * 8);
#pragma unroll
            for (int i = 0; i < 4; i++)
#pragma unroll
                for (int j = 0; j < 4; j++)
                    acc[i][j] = __builtin_amdgcn_mfma_f32_16x16x32_f16(af[i], bf[j], acc[i][j], 0, 0, 0);
        }
        __syncthreads();
    }

    // epilogue. C/D layout: col = lane&15, row = (lane>>4)*4 + reg
    float biasv[4];
#pragma unroll
    for (int j = 0; j < 4; j++) biasv[j] = bias[n0 + wn * 64 + j * 16 + m16];

#pragma unroll
    for (int i = 0; i < 4; i++) {
#pragma unroll
        for (int r = 0; r < 4; r++) {
            int rowp = m0 + wm * 64 + i * 16 + q * 4 + r;
            if (rowp >= mEnd) continue;
            int tok = 0; float wgt = 0.f;
            if constexpr (MODE == FC2R) { tok = rowsIdx[rowp]; wgt = rw[rowp]; }
#pragma unroll
            for (int j = 0; j < 4; j++) {
                int col = n0 + wn * 64 + j * 16 + m16;
                float v = acc[i][j][r] + biasv[j];
                if constexpr (MODE == FC1S || MODE == FC1R) {
                    v = 0.5f * v * (1.f + erff(v * 0.70710678118f));   // exact gelu
                    h[(size_t)rowp * FDIM + col] = (_Float16)v;
                } else if constexpr (MODE == FC2S) {
                    out[(size_t)rowp * DDIM + col] = v;                // rowp == token
                } else {
                    atomicAdd(&out[(size_t)tok * DDIM + col], v * wgt);
                }
            }
        }
    }
}

// ---------------- launch ----------------
extern "C" void kernel_launch(void* const* d_in, const int* in_sizes, int n_in,
                              void* d_out, int out_size, void* d_ws, size_t ws_size,
                              hipStream_t stream) {
    const float* x   = (const float*)d_in[0];
    const float* gw  = (const float*)d_in[1];
    const float* w1  = (const float*)d_in[2];
    const float* b1  = (const float*)d_in[3];
    const float* w2  = (const float*)d_in[4];
    const float* b2  = (const float*)d_in[5];
    const float* ws1 = (const float*)d_in[6];
    const float* bs1 = (const float*)d_in[7];
    const float* ws2 = (const float*)d_in[8];
    const float* bs2 = (const float*)d_in[9];
    float* out = (float*)d_out;
    char* ws = (char*)d_ws;
    if (ws_size < WS_NEED) return;   // fail loudly (output stays zero)

    _Float16* xh   = (_Float16*)(ws + XH_OFF);
    _Float16* w1h  = (_Float16*)(ws + W1H_OFF);
    _Float16* w2h  = (_Float16*)(ws + W2H_OFF);
    _Float16* ws1h = (_Float16*)(ws + WS1H_OFF);
    _Float16* ws2h = (_Float16*)(ws + WS2H_OFF);
    _Float16* h    = (_Float16*)(ws + H_OFF);
    int*   rowsIdx = (int*)(ws + ROWS_OFF);
    float* rw      = (float*)(ws + RW_OFF);
    int*   tidx    = (int*)(ws + TIDX_OFF);
    float* tw      = (float*)(ws + TW_OFF);
    int*   cnt     = (int*)(ws + CNT_OFF);
    int*   base    = (int*)(ws + BASE_OFF);
    int*   cur     = (int*)(ws + CUR_OFF);

    hipMemsetAsync(cnt, 0, E_EXP * sizeof(int), stream);

    // conversions to fp16
    cvt_f32_f16<<<6144,  256, 0, stream>>>(x,   xh,   1572864);   // 8192*768/4
    cvt_f32_f16<<<18432, 256, 0, stream>>>(w1,  w1h,  4718592);   // 8*3072*768/4
    cvt_f32_f16<<<18432, 256, 0, stream>>>(w2,  w2h,  4718592);
    cvt_f32_f16<<<2304,  256, 0, stream>>>(ws1, ws1h, 589824);    // 3072*768/4
    cvt_f32_f16<<<2304,  256, 0, stream>>>(ws2, ws2h, 589824);

    // routing
    gate_kernel<<<2048, 256, 0, stream>>>(x, gw, tidx, tw, cnt);
    offsets_kernel<<<1, 64, 0, stream>>>(cnt, base, cur);
    scatter_kernel<<<32, 256, 0, stream>>>(tidx, tw, cur, rowsIdx, rw);

    // shared expert (uses h rows [0,8192)), then routed (reuses h rows [0,16384))
    gemm_kernel<FC1S><<<dim3(64, 24),  256, 0, stream>>>(xh, ws1h, bs1, h, out, cnt, base, rowsIdx, rw);
    gemm_kernel<FC2S><<<dim3(64, 6),   256, 0, stream>>>(h,  ws2h, bs2, h, out, cnt, base, rowsIdx, rw);
    gemm_kernel<FC1R><<<dim3(136, 24), 256, 0, stream>>>(xh, w1h,  b1,  h, out, cnt, base, rowsIdx, rw);
    gemm_kernel<FC2R><<<dim3(136, 6),  256, 0, stream>>>(h,  w2h,  b2,  h, out, cnt, base, rowsIdx, rw);
}

// Round 2
// 720.142 us; speedup vs baseline: 1.3265x; 1.3265x over previous
//
#include <hip/hip_runtime.h>
#include <hip/hip_bf16.h>

#define T_TOK 8192
#define E_EXP 8
#define DDIM  768
#define FDIM  3072

typedef _Float16 f16x8 __attribute__((ext_vector_type(8)));
typedef _Float16 f16x4 __attribute__((ext_vector_type(4)));
typedef float    f32x4 __attribute__((ext_vector_type(4)));

// ---------------- workspace layout (bytes, all 256-aligned) ----------------
static const size_t XH_OFF   = 0;                         // 8192*768*2   = 12,582,912
static const size_t W1H_OFF  = 12582912;                  // 8*3072*768*2 = 37,748,736
static const size_t W2H_OFF  = 50331648;                  // 37,748,736
static const size_t WS1H_OFF = 88080384;                  // 4,718,592
static const size_t WS2H_OFF = 92798976;                  // 4,718,592
static const size_t H_OFF    = 97517568;                  // 16384*3072*2 = 100,663,296
static const size_t ROWS_OFF = 198180864;                 // 65,536
static const size_t RW_OFF   = 198246400;                 // 65,536
static const size_t TIDX_OFF = 198311936;                 // 65,536
static const size_t TW_OFF   = 198377472;                 // 65,536
static const size_t CNT_OFF  = 198443008;                 // 256
static const size_t BASE_OFF = 198443264;                 // 256
static const size_t CUR_OFF  = 198443520;                 // 256
static const size_t WS_NEED  = 198443776;

// ---------------- fp32 -> fp16 convert (vectorized) ----------------
__global__ void cvt_f32_f16(const float* __restrict__ src, _Float16* __restrict__ dst, int n4) {
    int i = blockIdx.x * blockDim.x + threadIdx.x;
    if (i >= n4) return;
    float4 v = ((const float4*)src)[i];
    f16x4 o = { (_Float16)v.x, (_Float16)v.y, (_Float16)v.z, (_Float16)v.w };
    *(f16x4*)(dst + 4 * (size_t)i) = o;
}

// ---------------- gate: fp32 logits, top-2, renormalized weights ----------------
// NO atomics (R1: 16384 contended atomicAdds made this the top dispatch at 195us)
__global__ void gate_kernel(const float* __restrict__ x, const float* __restrict__ gw,
                            int* __restrict__ tidx, float* __restrict__ tw) {
    int wave = threadIdx.x >> 6;
    int lane = threadIdx.x & 63;
    int t = blockIdx.x * 4 + wave;
    const float4* xv = (const float4*)(x + (size_t)t * DDIM);
    float p[E_EXP];
#pragma unroll
    for (int e = 0; e < E_EXP; e++) p[e] = 0.f;
    for (int i = lane; i < DDIM / 4; i += 64) {
        float4 xv4 = xv[i];
#pragma unroll
        for (int e = 0; e < E_EXP; e++) {
            float4 g = ((const float4*)(gw + (size_t)e * DDIM))[i];
            p[e] += xv4.x * g.x + xv4.y * g.y + xv4.z * g.z + xv4.w * g.w;
        }
    }
#pragma unroll
    for (int e = 0; e < E_EXP; e++) {
#pragma unroll
        for (int off = 32; off; off >>= 1) p[e] += __shfl_xor(p[e], off);
    }
    if (lane == 0) {
        int i0 = 0;
#pragma unroll
        for (int e = 1; e < E_EXP; e++) if (p[e] > p[i0]) i0 = e;
        int i1 = (i0 == 0) ? 1 : 0;
#pragma unroll
        for (int e = 0; e < E_EXP; e++) {
            if (e == i0) continue;
            if (p[e] > p[i1]) i1 = e;
        }
        // renormalized top-2 softmax depends only on the two logits
        float d  = p[i1] - p[i0];          // <= 0
        float e1 = expf(d);
        float w0 = 1.f / (1.f + e1);
        float w1 = 1.f - w0;
        tidx[2 * t]     = i0;  tw[2 * t]     = w0;
        tidx[2 * t + 1] = i1;  tw[2 * t + 1] = w1;
    }
}

// ---------------- count: single block, register histograms, zero atomics ----------------
__global__ void count_kernel(const int* __restrict__ tidx, int* __restrict__ cnt,
                             int* __restrict__ base, int* __restrict__ cur) {
    int c[E_EXP];
#pragma unroll
    for (int e = 0; e < E_EXP; e++) c[e] = 0;
    for (int i = threadIdx.x; i < 2 * T_TOK; i += 1024) {
        int e = tidx[i];
#pragma unroll
        for (int k = 0; k < E_EXP; k++) c[k] += (e == k) ? 1 : 0;
    }
#pragma unroll
    for (int e = 0; e < E_EXP; e++) {
#pragma unroll
        for (int off = 32; off; off >>= 1) c[e] += __shfl_xor(c[e], off);
    }
    __shared__ int wsum[16][E_EXP];
    int lane = threadIdx.x & 63, wave = threadIdx.x >> 6;
    if (lane == 0) {
#pragma unroll
        for (int e = 0; e < E_EXP; e++) wsum[wave][e] = c[e];
    }
    __syncthreads();
    if (threadIdx.x == 0) {
        int acc = 0;
        for (int e = 0; e < E_EXP; e++) {
            int s = 0;
            for (int w = 0; w < 16; w++) s += wsum[w][e];
            cnt[e] = s; base[e] = acc; cur[e] = acc; acc += s;
        }
    }
}

// ---------------- scatter: ballot ranking, 8 atomics per block ----------------
__global__ void scatter_kernel(const int* __restrict__ tidx, const float* __restrict__ tw,
                               int* __restrict__ cur, int* __restrict__ rowsIdx,
                               float* __restrict__ rw) {
    int t = blockIdx.x * 256 + threadIdx.x;
    int lane = threadIdx.x & 63, wave = threadIdx.x >> 6;
    unsigned long long lt = (lane == 63) ? 0x7FFFFFFFFFFFFFFFull
                                         : ((1ull << lane) - 1ull) | 0ull;
    lt = ((unsigned long long)1 << lane) - 1ull;   // lanes below me
    __shared__ int wcnt[8][E_EXP];     // [virtual wave][expert] counts
    __shared__ int wpre[8][E_EXP];     // exclusive prefix over virtual waves
    __shared__ int bbase[E_EXP];       // block base from global atomic

    int myE[2], myR[2];
#pragma unroll
    for (int k = 0; k < 2; k++) {
        int e = tidx[2 * t + k];
        myE[k] = e;
        int vw = wave * 2 + k;
        int rank = 0;
#pragma unroll
        for (int ee = 0; ee < E_EXP; ee++) {
            unsigned long long m = __ballot(e == ee);
            if (e == ee) rank = __builtin_popcountll(m & lt);
            if (lane == 0) wcnt[vw][ee] = __builtin_popcountll(m);
        }
        myR[k] = rank;
    }
    __syncthreads();
    if (threadIdx.x < E_EXP) {
        int e = threadIdx.x, acc = 0;
#pragma unroll
        for (int vw = 0; vw < 8; vw++) { wpre[vw][e] = acc; acc += wcnt[vw][e]; }
        bbase[e] = atomicAdd(&cur[e], acc);
    }
    __syncthreads();
#pragma unroll
    for (int k = 0; k < 2; k++) {
        int e = myE[k];
        int slot = bbase[e] + wpre[wave * 2 + k][e] + myR[k];
        rowsIdx[slot] = t;
        rw[slot] = tw[2 * t + k];
    }
}

// ---------------- MFMA GEMM, 128x128 tile, BK=64, 4 waves ----------------
// Modes: 0=FC1 shared  1=FC2 shared  2=FC1 routed  3=FC2 routed
#define FC1S 0
#define FC2S 1
#define FC1R 2
#define FC2R 3

template <int MODE>
__global__ __launch_bounds__(256, 2) void gemm_kernel(
    const _Float16* __restrict__ Abase,   // xh (fc1) or h (fc2), lda == K
    const _Float16* __restrict__ Wbase,   // [N,K] row-major (per expert for routed)
    const float* __restrict__ biasBase,
    _Float16* __restrict__ h,             // fc1 output
    float* __restrict__ out,              // fc2 output
    const int* __restrict__ cnt, const int* __restrict__ base,
    const int* __restrict__ rowsIdx, const float* __restrict__ rw)
{
    constexpr int K = (MODE == FC1S || MODE == FC1R) ? DDIM : FDIM;
    constexpr int N = (MODE == FC1S || MODE == FC1R) ? FDIM : DDIM;
    constexpr bool ROUTED = (MODE == FC1R || MODE == FC2R);

    int m0, mEnd;
    const _Float16* W;
    const float* bias;
    if constexpr (ROUTED) {
        int bx = blockIdx.x, accb = 0, expert = -1, rb = 0;
#pragma unroll
        for (int e = 0; e < E_EXP; e++) {
            int nb = (cnt[e] + 127) >> 7;
            if (expert < 0 && bx < accb + nb) { expert = e; rb = bx - accb; }
            accb += nb;
        }
        if (expert < 0) return;
        m0   = base[expert] + rb * 128;
        mEnd = base[expert] + cnt[expert];
        W    = Wbase + (size_t)expert * N * K;
        bias = biasBase + (size_t)expert * N;
    } else {
        m0 = blockIdx.x * 128;
        mEnd = T_TOK;
        W = Wbase;
        bias = biasBase;
    }
    int n0 = blockIdx.y * 128;

    __shared__ __align__(16) _Float16 As[128 * 72];   // stride 72 elems = 144B: 16B-aligned, 2-way bank alias (free)
    __shared__ __align__(16) _Float16 Bs[128 * 72];

    int tid  = threadIdx.x;
    int lane = tid & 63;
    int wid  = tid >> 6;
    int wm   = wid >> 1, wn = wid & 1;
    int m16  = lane & 15, q = lane >> 4;

    f32x4 acc[4][4];
#pragma unroll
    for (int i = 0; i < 4; i++)
#pragma unroll
        for (int j = 0; j < 4; j++) acc[i][j] = f32x4{0.f, 0.f, 0.f, 0.f};

    // A-row indices for this thread's 4 staging segments (fixed across K)
    int arowg[4];
#pragma unroll
    for (int tse = 0; tse < 4; tse++) {
        int s = tid + tse * 256;
        int row = s >> 3;
        int pr = m0 + row;
        bool valid = pr < mEnd;
        int ar;
        if constexpr (MODE == FC1R) ar = valid ? rowsIdx[pr] : 0;
        else                        ar = pr;
        arowg[tse] = valid ? ar : -1;
    }

    for (int k0 = 0; k0 < K; k0 += 64) {
#pragma unroll
        for (int tse = 0; tse < 4; tse++) {
            int s = tid + tse * 256;
            int row = s >> 3, cs = s & 7;
            int4 v = make_int4(0, 0, 0, 0);
            int ar = arowg[tse];
            if (ar >= 0) v = *(const int4*)(Abase + (size_t)ar * K + k0 + cs * 8);
            *(int4*)(As + row * 72 + cs * 8) = v;
        }
#pragma unroll
        for (int tse = 0; tse < 4; tse++) {
            int s = tid + tse * 256;
            int row = s >> 3, cs = s & 7;
            int4 v = *(const int4*)(W + (size_t)(n0 + row) * K + k0 + cs * 8);
            *(int4*)(Bs + row * 72 + cs * 8) = v;
        }
        __syncthreads();
#pragma unroll
        for (int ks = 0; ks < 2; ks++) {
            f16x8 af[4], bf[4];
#pragma unroll
            for (int i = 0; i < 4; i++)
                af[i] = *(const f16x8*)(As + (wm * 64 + i * 16 + m16) * 72 + ks * 32 + q * 8);
#pragma unroll
            for (int j = 0; j < 4; j++)
                bf[j] = *(const f16x8*)(Bs + (wn * 64 + j * 16 + m16) * 72 + ks * 32 + q * 8);
#pragma unroll
            for (int i = 0; i < 4; i++)
#pragma unroll
                for (int j = 0; j < 4; j++)
                    acc[i][j] = __builtin_amdgcn_mfma_f32_16x16x32_f16(af[i], bf[j], acc[i][j], 0, 0, 0);
        }
        __syncthreads();
    }

    // epilogue. C/D layout: col = lane&15, row = (lane>>4)*4 + reg
    float biasv[4];
#pragma unroll
    for (int j = 0; j < 4; j++) biasv[j] = bias[n0 + wn * 64 + j * 16 + m16];

#pragma unroll
    for (int i = 0; i < 4; i++) {
#pragma unroll
        for (int r = 0; r < 4; r++) {
            int rowp = m0 + wm * 64 + i * 16 + q * 4 + r;
            if (rowp >= mEnd) continue;
            int tok = 0; float wgt = 0.f;
            if constexpr (MODE == FC2R) { tok = rowsIdx[rowp]; wgt = rw[rowp]; }
#pragma unroll
            for (int j = 0; j < 4; j++) {
                int col = n0 + wn * 64 + j * 16 + m16;
                float v = acc[i][j][r] + biasv[j];
                if constexpr (MODE == FC1S || MODE == FC1R) {
                    v = 0.5f * v * (1.f + erff(v * 0.70710678118f));   // exact gelu
                    h[(size_t)rowp * FDIM + col] = (_Float16)v;
                } else if constexpr (MODE == FC2S) {
                    out[(size_t)rowp * DDIM + col] = v;                // rowp == token
                } else {
                    atomicAdd(&out[(size_t)tok * DDIM + col], v * wgt);
                }
            }
        }
    }
}

// ---------------- launch ----------------
extern "C" void kernel_launch(void* const* d_in, const int* in_sizes, int n_in,
                              void* d_out, int out_size, void* d_ws, size_t ws_size,
                              hipStream_t stream) {
    const float* x   = (const float*)d_in[0];
    const float* gw  = (const float*)d_in[1];
    const float* w1  = (const float*)d_in[2];
    const float* b1  = (const float*)d_in[3];
    const float* w2  = (const float*)d_in[4];
    const float* b2  = (const float*)d_in[5];
    const float* ws1 = (const float*)d_in[6];
    const float* bs1 = (const float*)d_in[7];
    const float* ws2 = (const float*)d_in[8];
    const float* bs2 = (const float*)d_in[9];
    float* out = (float*)d_out;
    char* ws = (char*)d_ws;
    if (ws_size < WS_NEED) return;   // fail loudly (output stays zero)

    _Float16* xh   = (_Float16*)(ws + XH_OFF);
    _Float16* w1h  = (_Float16*)(ws + W1H_OFF);
    _Float16* w2h  = (_Float16*)(ws + W2H_OFF);
    _Float16* ws1h = (_Float16*)(ws + WS1H_OFF);
    _Float16* ws2h = (_Float16*)(ws + WS2H_OFF);
    _Float16* h    = (_Float16*)(ws + H_OFF);
    int*   rowsIdx = (int*)(ws + ROWS_OFF);
    float* rw      = (float*)(ws + RW_OFF);
    int*   tidx    = (int*)(ws + TIDX_OFF);
    float* tw      = (float*)(ws + TW_OFF);
    int*   cnt     = (int*)(ws + CNT_OFF);
    int*   base    = (int*)(ws + BASE_OFF);
    int*   cur     = (int*)(ws + CUR_OFF);

    // conversions to fp16
    cvt_f32_f16<<<6144,  256, 0, stream>>>(x,   xh,   1572864);   // 8192*768/4
    cvt_f32_f16<<<18432, 256, 0, stream>>>(w1,  w1h,  4718592);   // 8*3072*768/4
    cvt_f32_f16<<<18432, 256, 0, stream>>>(w2,  w2h,  4718592);
    cvt_f32_f16<<<2304,  256, 0, stream>>>(ws1, ws1h, 589824);    // 3072*768/4
    cvt_f32_f16<<<2304,  256, 0, stream>>>(ws2, ws2h, 589824);

    // routing (atomic-free count + low-contention scatter)
    gate_kernel<<<2048, 256, 0, stream>>>(x, gw, tidx, tw);
    count_kernel<<<1, 1024, 0, stream>>>(tidx, cnt, base, cur);
    scatter_kernel<<<32, 256, 0, stream>>>(tidx, tw, cur, rowsIdx, rw);

    // shared expert (uses h rows [0,8192)), then routed (reuses h rows [0,16384))
    gemm_kernel<FC1S><<<dim3(64, 24),  256, 0, stream>>>(xh, ws1h, bs1, h, out, cnt, base, rowsIdx, rw);
    gemm_kernel<FC2S><<<dim3(64, 6),   256, 0, stream>>>(h,  ws2h, bs2, h, out, cnt, base, rowsIdx, rw);
    gemm_kernel<FC1R><<<dim3(136, 24), 256, 0, stream>>>(xh, w1h,  b1,  h, out, cnt, base, rowsIdx, rw);
    gemm_kernel<FC2R><<<dim3(136, 6),  256, 0, stream>>>(h,  w2h,  b2,  h, out, cnt, base, rowsIdx, rw);
}

// Round 3
// 714.669 us; speedup vs baseline: 1.3367x; 1.0077x over previous
//
#include <hip/hip_runtime.h>
#include <hip/hip_bf16.h>

#define T_TOK 8192
#define E_EXP 8
#define DDIM  768
#define FDIM  3072

typedef _Float16 f16x8 __attribute__((ext_vector_type(8)));
typedef _Float16 f16x4 __attribute__((ext_vector_type(4)));
typedef float    f32x4 __attribute__((ext_vector_type(4)));

// ---------------- workspace layout (bytes, all 256-aligned) ----------------
static const size_t XH_OFF   = 0;                         // 8192*768*2   = 12,582,912
static const size_t W1H_OFF  = 12582912;                  // 8*3072*768*2 = 37,748,736
static const size_t Y_OFF    = W1H_OFF;                   // y[16384*768] f16 = 25,165,824  (reuses w1h region after FC1R is done)
static const size_t W2H_OFF  = 50331648;                  // 37,748,736
static const size_t WS1H_OFF = 88080384;                  // 4,718,592
static const size_t WS2H_OFF = 92798976;                  // 4,718,592
static const size_t H_OFF    = 97517568;                  // 16384*3072*2 = 100,663,296
static const size_t ROWS_OFF = 198180864;                 // 65,536
static const size_t RW_OFF   = 198246400;                 // 65,536
static const size_t TIDX_OFF = 198311936;                 // 65,536
static const size_t TW_OFF   = 198377472;                 // 65,536
static const size_t CNT_OFF  = 198443008;                 // 256
static const size_t BASE_OFF = 198443264;                 // 256
static const size_t CUR_OFF  = 198443520;                 // 256
static const size_t TSLOT_OFF= 198443776;                 // 65,536 (token -> 2 slots inverse map)
static const size_t WS_NEED  = 198509312;

// ---------------- fp32 -> fp16 convert (vectorized) ----------------
__global__ void cvt_f32_f16(const float* __restrict__ src, _Float16* __restrict__ dst, int n4) {
    int i = blockIdx.x * blockDim.x + threadIdx.x;
    if (i >= n4) return;
    float4 v = ((const float4*)src)[i];
    f16x4 o = { (_Float16)v.x, (_Float16)v.y, (_Float16)v.z, (_Float16)v.w };
    *(f16x4*)(dst + 4 * (size_t)i) = o;
}

// ---------------- gate: fp32 logits, top-2, renormalized weights (no atomics) ----------------
__global__ void gate_kernel(const float* __restrict__ x, const float* __restrict__ gw,
                            int* __restrict__ tidx, float* __restrict__ tw) {
    int wave = threadIdx.x >> 6;
    int lane = threadIdx.x & 63;
    int t = blockIdx.x * 4 + wave;
    const float4* xv = (const float4*)(x + (size_t)t * DDIM);
    float p[E_EXP];
#pragma unroll
    for (int e = 0; e < E_EXP; e++) p[e] = 0.f;
    for (int i = lane; i < DDIM / 4; i += 64) {
        float4 xv4 = xv[i];
#pragma unroll
        for (int e = 0; e < E_EXP; e++) {
            float4 g = ((const float4*)(gw + (size_t)e * DDIM))[i];
            p[e] += xv4.x * g.x + xv4.y * g.y + xv4.z * g.z + xv4.w * g.w;
        }
    }
#pragma unroll
    for (int e = 0; e < E_EXP; e++) {
#pragma unroll
        for (int off = 32; off; off >>= 1) p[e] += __shfl_xor(p[e], off);
    }
    if (lane == 0) {
        int i0 = 0;
#pragma unroll
        for (int e = 1; e < E_EXP; e++) if (p[e] > p[i0]) i0 = e;
        int i1 = (i0 == 0) ? 1 : 0;
#pragma unroll
        for (int e = 0; e < E_EXP; e++) {
            if (e == i0) continue;
            if (p[e] > p[i1]) i1 = e;
        }
        float d  = p[i1] - p[i0];          // <= 0
        float e1 = expf(d);
        float w0 = 1.f / (1.f + e1);
        float w1 = 1.f - w0;
        tidx[2 * t]     = i0;  tw[2 * t]     = w0;
        tidx[2 * t + 1] = i1;  tw[2 * t + 1] = w1;
    }
}

// ---------------- count: single block, register histograms, zero atomics ----------------
__global__ void count_kernel(const int* __restrict__ tidx, int* __restrict__ cnt,
                             int* __restrict__ base, int* __restrict__ cur) {
    int c[E_EXP];
#pragma unroll
    for (int e = 0; e < E_EXP; e++) c[e] = 0;
    for (int i = threadIdx.x; i < 2 * T_TOK; i += 1024) {
        int e = tidx[i];
#pragma unroll
        for (int k = 0; k < E_EXP; k++) c[k] += (e == k) ? 1 : 0;
    }
#pragma unroll
    for (int e = 0; e < E_EXP; e++) {
#pragma unroll
        for (int off = 32; off; off >>= 1) c[e] += __shfl_xor(c[e], off);
    }
    __shared__ int wsum[16][E_EXP];
    int lane = threadIdx.x & 63, wave = threadIdx.x >> 6;
    if (lane == 0) {
#pragma unroll
        for (int e = 0; e < E_EXP; e++) wsum[wave][e] = c[e];
    }
    __syncthreads();
    if (threadIdx.x == 0) {
        int acc = 0;
        for (int e = 0; e < E_EXP; e++) {
            int s = 0;
            for (int w = 0; w < 16; w++) s += wsum[w][e];
            cnt[e] = s; base[e] = acc; cur[e] = acc; acc += s;
        }
    }
}

// ---------------- scatter: ballot ranking, 8 atomics per block; writes inverse map ----------------
__global__ void scatter_kernel(const int* __restrict__ tidx, const float* __restrict__ tw,
                               int* __restrict__ cur, int* __restrict__ rowsIdx,
                               float* __restrict__ rw, int* __restrict__ tslot) {
    int t = blockIdx.x * 256 + threadIdx.x;
    int lane = threadIdx.x & 63, wave = threadIdx.x >> 6;
    unsigned long long lt = ((unsigned long long)1 << lane) - 1ull;   // lanes below me
    __shared__ int wcnt[8][E_EXP];     // [virtual wave][expert] counts
    __shared__ int wpre[8][E_EXP];     // exclusive prefix over virtual waves
    __shared__ int bbase[E_EXP];       // block base from global atomic

    int myE[2], myR[2];
#pragma unroll
    for (int k = 0; k < 2; k++) {
        int e = tidx[2 * t + k];
        myE[k] = e;
        int vw = wave * 2 + k;
        int rank = 0;
#pragma unroll
        for (int ee = 0; ee < E_EXP; ee++) {
            unsigned long long m = __ballot(e == ee);
            if (e == ee) rank = __builtin_popcountll(m & lt);
            if (lane == 0) wcnt[vw][ee] = __builtin_popcountll(m);
        }
        myR[k] = rank;
    }
    __syncthreads();
    if (threadIdx.x < E_EXP) {
        int e = threadIdx.x, acc = 0;
#pragma unroll
        for (int vw = 0; vw < 8; vw++) { wpre[vw][e] = acc; acc += wcnt[vw][e]; }
        bbase[e] = atomicAdd(&cur[e], acc);
    }
    __syncthreads();
#pragma unroll
    for (int k = 0; k < 2; k++) {
        int e = myE[k];
        int slot = bbase[e] + wpre[wave * 2 + k][e] + myR[k];
        rowsIdx[slot] = t;
        rw[slot] = tw[2 * t + k];
        tslot[2 * t + k] = slot;
    }
}

// ---------------- combine: out[t] += y[s0] + y[s1]  (y already weighted) ----------------
__global__ void combine_kernel(const _Float16* __restrict__ y,
                               const int* __restrict__ tslot,
                               float* __restrict__ out) {
    int idx = blockIdx.x * 256 + threadIdx.x;   // one 8-elem chunk per thread
    int t = idx / (DDIM / 8);
    int c = (idx % (DDIM / 8)) * 8;
    int s0 = tslot[2 * t], s1 = tslot[2 * t + 1];
    f16x8 a = *(const f16x8*)(y + (size_t)s0 * DDIM + c);
    f16x8 b = *(const f16x8*)(y + (size_t)s1 * DDIM + c);
    float4* o = (float4*)(out + (size_t)t * DDIM + c);
    float4 o0 = o[0], o1 = o[1];
    o0.x += (float)a[0] + (float)b[0];
    o0.y += (float)a[1] + (float)b[1];
    o0.z += (float)a[2] + (float)b[2];
    o0.w += (float)a[3] + (float)b[3];
    o1.x += (float)a[4] + (float)b[4];
    o1.y += (float)a[5] + (float)b[5];
    o1.z += (float)a[6] + (float)b[6];
    o1.w += (float)a[7] + (float)b[7];
    o[0] = o0; o[1] = o1;
}

// ---------------- MFMA GEMM, 128x128 tile, BK=64, 4 waves ----------------
// Modes: 0=FC1 shared  1=FC2 shared  2=FC1 routed  3=FC2 routed
#define FC1S 0
#define FC2S 1
#define FC1R 2
#define FC2R 3

template <int MODE>
__global__ __launch_bounds__(256, 2) void gemm_kernel(
    const _Float16* __restrict__ Abase,   // xh (fc1) or h (fc2), lda == K
    const _Float16* __restrict__ Wbase,   // [N,K] row-major (per expert for routed)
    const float* __restrict__ biasBase,
    _Float16* __restrict__ h,             // fc1 output; y scratch for FC2R
    float* __restrict__ out,              // fc2 shared output
    const int* __restrict__ cnt, const int* __restrict__ base,
    const int* __restrict__ rowsIdx, const float* __restrict__ rw)
{
    constexpr int K = (MODE == FC1S || MODE == FC1R) ? DDIM : FDIM;
    constexpr int N = (MODE == FC1S || MODE == FC1R) ? FDIM : DDIM;
    constexpr bool ROUTED = (MODE == FC1R || MODE == FC2R);

    int m0, mEnd;
    const _Float16* W;
    const float* bias;
    if constexpr (ROUTED) {
        int bx = blockIdx.x, accb = 0, expert = -1, rb = 0;
#pragma unroll
        for (int e = 0; e < E_EXP; e++) {
            int nb = (cnt[e] + 127) >> 7;
            if (expert < 0 && bx < accb + nb) { expert = e; rb = bx - accb; }
            accb += nb;
        }
        if (expert < 0) return;
        m0   = base[expert] + rb * 128;
        mEnd = base[expert] + cnt[expert];
        W    = Wbase + (size_t)expert * N * K;
        bias = biasBase + (size_t)expert * N;
    } else {
        m0 = blockIdx.x * 128;
        mEnd = T_TOK;
        W = Wbase;
        bias = biasBase;
    }
    int n0 = blockIdx.y * 128;

    __shared__ __align__(16) _Float16 As[128 * 72];   // stride 72 elems = 144B: 16B-aligned, 2-way bank alias (free)
    __shared__ __align__(16) _Float16 Bs[128 * 72];

    int tid  = threadIdx.x;
    int lane = tid & 63;
    int wid  = tid >> 6;
    int wm   = wid >> 1, wn = wid & 1;
    int m16  = lane & 15, q = lane >> 4;

    f32x4 acc[4][4];
#pragma unroll
    for (int i = 0; i < 4; i++)
#pragma unroll
        for (int j = 0; j < 4; j++) acc[i][j] = f32x4{0.f, 0.f, 0.f, 0.f};

    // A-row indices for this thread's 4 staging segments (fixed across K)
    int arowg[4];
#pragma unroll
    for (int tse = 0; tse < 4; tse++) {
        int s = tid + tse * 256;
        int row = s >> 3;
        int pr = m0 + row;
        bool valid = pr < mEnd;
        int ar;
        if constexpr (MODE == FC1R) ar = valid ? rowsIdx[pr] : 0;
        else                        ar = pr;
        arowg[tse] = valid ? ar : -1;
    }

    for (int k0 = 0; k0 < K; k0 += 64) {
#pragma unroll
        for (int tse = 0; tse < 4; tse++) {
            int s = tid + tse * 256;
            int row = s >> 3, cs = s & 7;
            int4 v = make_int4(0, 0, 0, 0);
            int ar = arowg[tse];
            if (ar >= 0) v = *(const int4*)(Abase + (size_t)ar * K + k0 + cs * 8);
            *(int4*)(As + row * 72 + cs * 8) = v;
        }
#pragma unroll
        for (int tse = 0; tse < 4; tse++) {
            int s = tid + tse * 256;
            int row = s >> 3, cs = s & 7;
            int4 v = *(const int4*)(W + (size_t)(n0 + row) * K + k0 + cs * 8);
            *(int4*)(Bs + row * 72 + cs * 8) = v;
        }
        __syncthreads();
#pragma unroll
        for (int ks = 0; ks < 2; ks++) {
            f16x8 af[4], bf[4];
#pragma unroll
            for (int i = 0; i < 4; i++)
                af[i] = *(const f16x8*)(As + (wm * 64 + i * 16 + m16) * 72 + ks * 32 + q * 8);
#pragma unroll
            for (int j = 0; j < 4; j++)
                bf[j] = *(const f16x8*)(Bs + (wn * 64 + j * 16 + m16) * 72 + ks * 32 + q * 8);
#pragma unroll
            for (int i = 0; i < 4; i++)
#pragma unroll
                for (int j = 0; j < 4; j++)
                    acc[i][j] = __builtin_amdgcn_mfma_f32_16x16x32_f16(af[i], bf[j], acc[i][j], 0, 0, 0);
        }
        __syncthreads();
    }

    // epilogue. C/D layout: col = lane&15, row = (lane>>4)*4 + reg
    float biasv[4];
#pragma unroll
    for (int j = 0; j < 4; j++) biasv[j] = bias[n0 + wn * 64 + j * 16 + m16];

#pragma unroll
    for (int i = 0; i < 4; i++) {
#pragma unroll
        for (int r = 0; r < 4; r++) {
            int rowp = m0 + wm * 64 + i * 16 + q * 4 + r;
            if (rowp >= mEnd) continue;
            float wgt = 0.f;
            if constexpr (MODE == FC2R) wgt = rw[rowp];
#pragma unroll
            for (int j = 0; j < 4; j++) {
                int col = n0 + wn * 64 + j * 16 + m16;
                float v = acc[i][j][r] + biasv[j];
                if constexpr (MODE == FC1S || MODE == FC1R) {
                    v = 0.5f * v * (1.f + erff(v * 0.70710678118f));   // exact gelu
                    h[(size_t)rowp * FDIM + col] = (_Float16)v;
                } else if constexpr (MODE == FC2S) {
                    out[(size_t)rowp * DDIM + col] = v;                // rowp == token
                } else {                                               // FC2R: weighted f16 to y (h param)
                    h[(size_t)rowp * DDIM + col] = (_Float16)(v * wgt);
                }
            }
        }
    }
}

// ---------------- launch ----------------
extern "C" void kernel_launch(void* const* d_in, const int* in_sizes, int n_in,
                              void* d_out, int out_size, void* d_ws, size_t ws_size,
                              hipStream_t stream) {
    const float* x   = (const float*)d_in[0];
    const float* gw  = (const float*)d_in[1];
    const float* w1  = (const float*)d_in[2];
    const float* b1  = (const float*)d_in[3];
    const float* w2  = (const float*)d_in[4];
    const float* b2  = (const float*)d_in[5];
    const float* ws1 = (const float*)d_in[6];
    const float* bs1 = (const float*)d_in[7];
    const float* ws2 = (const float*)d_in[8];
    const float* bs2 = (const float*)d_in[9];
    float* out = (float*)d_out;
    char* ws = (char*)d_ws;
    if (ws_size < WS_NEED) return;   // fail loudly (output stays zero)

    _Float16* xh   = (_Float16*)(ws + XH_OFF);
    _Float16* w1h  = (_Float16*)(ws + W1H_OFF);
    _Float16* yb   = (_Float16*)(ws + Y_OFF);     // aliases w1h (dead after FC1R)
    _Float16* w2h  = (_Float16*)(ws + W2H_OFF);
    _Float16* ws1h = (_Float16*)(ws + WS1H_OFF);
    _Float16* ws2h = (_Float16*)(ws + WS2H_OFF);
    _Float16* h    = (_Float16*)(ws + H_OFF);
    int*   rowsIdx = (int*)(ws + ROWS_OFF);
    float* rw      = (float*)(ws + RW_OFF);
    int*   tidx    = (int*)(ws + TIDX_OFF);
    float* tw      = (float*)(ws + TW_OFF);
    int*   cnt     = (int*)(ws + CNT_OFF);
    int*   base    = (int*)(ws + BASE_OFF);
    int*   cur     = (int*)(ws + CUR_OFF);
    int*   tslot   = (int*)(ws + TSLOT_OFF);

    // conversions to fp16
    cvt_f32_f16<<<6144,  256, 0, stream>>>(x,   xh,   1572864);   // 8192*768/4
    cvt_f32_f16<<<18432, 256, 0, stream>>>(w1,  w1h,  4718592);   // 8*3072*768/4
    cvt_f32_f16<<<18432, 256, 0, stream>>>(w2,  w2h,  4718592);
    cvt_f32_f16<<<2304,  256, 0, stream>>>(ws1, ws1h, 589824);    // 3072*768/4
    cvt_f32_f16<<<2304,  256, 0, stream>>>(ws2, ws2h, 589824);

    // routing (atomic-free count + low-contention scatter)
    gate_kernel<<<2048, 256, 0, stream>>>(x, gw, tidx, tw);
    count_kernel<<<1, 1024, 0, stream>>>(tidx, cnt, base, cur);
    scatter_kernel<<<32, 256, 0, stream>>>(tidx, tw, cur, rowsIdx, rw, tslot);

    // shared expert, then routed; FC2R writes weighted f16 into yb (w1h region, dead after FC1R)
    gemm_kernel<FC1S><<<dim3(64, 24),  256, 0, stream>>>(xh, ws1h, bs1, h, out, cnt, base, rowsIdx, rw);
    gemm_kernel<FC2S><<<dim3(64, 6),   256, 0, stream>>>(h,  ws2h, bs2, h, out, cnt, base, rowsIdx, rw);
    gemm_kernel<FC1R><<<dim3(136, 24), 256, 0, stream>>>(xh, w1h,  b1,  h, out, cnt, base, rowsIdx, rw);
    gemm_kernel<FC2R><<<dim3(136, 6),  256, 0, stream>>>(h,  w2h,  b2,  yb, out, cnt, base, rowsIdx, rw);

    // final combine: out[t] += y[slot0] + y[slot1]
    combine_kernel<<<3072, 256, 0, stream>>>(yb, tslot, out);
}

// Round 4
// 594.681 us; speedup vs baseline: 1.6064x; 1.2018x over previous
//
#include <hip/hip_runtime.h>
#include <hip/hip_bf16.h>

#define T_TOK 8192
#define E_EXP 8
#define DDIM  768
#define FDIM  3072

typedef _Float16 f16x8 __attribute__((ext_vector_type(8)));
typedef _Float16 f16x4 __attribute__((ext_vector_type(4)));
typedef float    f32x4 __attribute__((ext_vector_type(4)));

// ---------------- workspace layout (bytes, all 256-aligned) ----------------
static const size_t XH_OFF   = 0;                         // 8192*768*2   = 12,582,912
static const size_t W1H_OFF  = 12582912;                  // 8*3072*768*2 = 37,748,736
static const size_t Y_OFF    = W1H_OFF;                   // y[16384*768] f16 (reuses w1h region after FC1R)
static const size_t W2H_OFF  = 50331648;                  // 37,748,736
static const size_t WS1H_OFF = 88080384;                  // 4,718,592
static const size_t WS2H_OFF = 92798976;                  // 4,718,592
static const size_t H_OFF    = 97517568;                  // 16384*3072*2 = 100,663,296
static const size_t ROWS_OFF = 198180864;                 // 65,536
static const size_t RW_OFF   = 198246400;                 // 65,536
static const size_t TIDX_OFF = 198311936;                 // 65,536
static const size_t TW_OFF   = 198377472;                 // 65,536
static const size_t CNT_OFF  = 198443008;                 // 256
static const size_t BASE_OFF = 198443264;                 // 256
static const size_t CUR_OFF  = 198443520;                 // 256
static const size_t TSLOT_OFF= 198443776;                 // 65,536 (token -> 2 slots inverse map)
static const size_t WS_NEED  = 198509312;

// ---------------- fp32 -> fp16 convert (vectorized) ----------------
__global__ void cvt_f32_f16(const float* __restrict__ src, _Float16* __restrict__ dst, int n4) {
    int i = blockIdx.x * blockDim.x + threadIdx.x;
    if (i >= n4) return;
    float4 v = ((const float4*)src)[i];
    f16x4 o = { (_Float16)v.x, (_Float16)v.y, (_Float16)v.z, (_Float16)v.w };
    *(f16x4*)(dst + 4 * (size_t)i) = o;
}

// ---------------- gate: fp32 logits, top-2, renormalized weights (no atomics) ----------------
__global__ void gate_kernel(const float* __restrict__ x, const float* __restrict__ gw,
                            int* __restrict__ tidx, float* __restrict__ tw) {
    int wave = threadIdx.x >> 6;
    int lane = threadIdx.x & 63;
    int t = blockIdx.x * 4 + wave;
    const float4* xv = (const float4*)(x + (size_t)t * DDIM);
    float p[E_EXP];
#pragma unroll
    for (int e = 0; e < E_EXP; e++) p[e] = 0.f;
    for (int i = lane; i < DDIM / 4; i += 64) {
        float4 xv4 = xv[i];
#pragma unroll
        for (int e = 0; e < E_EXP; e++) {
            float4 g = ((const float4*)(gw + (size_t)e * DDIM))[i];
            p[e] += xv4.x * g.x + xv4.y * g.y + xv4.z * g.z + xv4.w * g.w;
        }
    }
#pragma unroll
    for (int e = 0; e < E_EXP; e++) {
#pragma unroll
        for (int off = 32; off; off >>= 1) p[e] += __shfl_xor(p[e], off);
    }
    if (lane == 0) {
        int i0 = 0;
#pragma unroll
        for (int e = 1; e < E_EXP; e++) if (p[e] > p[i0]) i0 = e;
        int i1 = (i0 == 0) ? 1 : 0;
#pragma unroll
        for (int e = 0; e < E_EXP; e++) {
            if (e == i0) continue;
            if (p[e] > p[i1]) i1 = e;
        }
        float d  = p[i1] - p[i0];          // <= 0
        float e1 = expf(d);
        float w0 = 1.f / (1.f + e1);
        float w1 = 1.f - w0;
        tidx[2 * t]     = i0;  tw[2 * t]     = w0;
        tidx[2 * t + 1] = i1;  tw[2 * t + 1] = w1;
    }
}

// ---------------- count: single block, register histograms, zero atomics ----------------
__global__ void count_kernel(const int* __restrict__ tidx, int* __restrict__ cnt,
                             int* __restrict__ base, int* __restrict__ cur) {
    int c[E_EXP];
#pragma unroll
    for (int e = 0; e < E_EXP; e++) c[e] = 0;
    for (int i = threadIdx.x; i < 2 * T_TOK; i += 1024) {
        int e = tidx[i];
#pragma unroll
        for (int k = 0; k < E_EXP; k++) c[k] += (e == k) ? 1 : 0;
    }
#pragma unroll
    for (int e = 0; e < E_EXP; e++) {
#pragma unroll
        for (int off = 32; off; off >>= 1) c[e] += __shfl_xor(c[e], off);
    }
    __shared__ int wsum[16][E_EXP];
    int lane = threadIdx.x & 63, wave = threadIdx.x >> 6;
    if (lane == 0) {
#pragma unroll
        for (int e = 0; e < E_EXP; e++) wsum[wave][e] = c[e];
    }
    __syncthreads();
    if (threadIdx.x == 0) {
        int acc = 0;
        for (int e = 0; e < E_EXP; e++) {
            int s = 0;
            for (int w = 0; w < 16; w++) s += wsum[w][e];
            cnt[e] = s; base[e] = acc; cur[e] = acc; acc += s;
        }
    }
}

// ---------------- scatter: ballot ranking, 8 atomics per block; writes inverse map ----------------
__global__ void scatter_kernel(const int* __restrict__ tidx, const float* __restrict__ tw,
                               int* __restrict__ cur, int* __restrict__ rowsIdx,
                               float* __restrict__ rw, int* __restrict__ tslot) {
    int t = blockIdx.x * 256 + threadIdx.x;
    int lane = threadIdx.x & 63, wave = threadIdx.x >> 6;
    unsigned long long lt = ((unsigned long long)1 << lane) - 1ull;   // lanes below me
    __shared__ int wcnt[8][E_EXP];
    __shared__ int wpre[8][E_EXP];
    __shared__ int bbase[E_EXP];

    int myE[2], myR[2];
#pragma unroll
    for (int k = 0; k < 2; k++) {
        int e = tidx[2 * t + k];
        myE[k] = e;
        int vw = wave * 2 + k;
        int rank = 0;
#pragma unroll
        for (int ee = 0; ee < E_EXP; ee++) {
            unsigned long long m = __ballot(e == ee);
            if (e == ee) rank = __builtin_popcountll(m & lt);
            if (lane == 0) wcnt[vw][ee] = __builtin_popcountll(m);
        }
        myR[k] = rank;
    }
    __syncthreads();
    if (threadIdx.x < E_EXP) {
        int e = threadIdx.x, acc = 0;
#pragma unroll
        for (int vw = 0; vw < 8; vw++) { wpre[vw][e] = acc; acc += wcnt[vw][e]; }
        bbase[e] = atomicAdd(&cur[e], acc);
    }
    __syncthreads();
#pragma unroll
    for (int k = 0; k < 2; k++) {
        int e = myE[k];
        int slot = bbase[e] + wpre[wave * 2 + k][e] + myR[k];
        rowsIdx[slot] = t;
        rw[slot] = tw[2 * t + k];
        tslot[2 * t + k] = slot;
    }
}

// ---------------- combine: out[t] += y[s0] + y[s1]  (y already weighted) ----------------
__global__ void combine_kernel(const _Float16* __restrict__ y,
                               const int* __restrict__ tslot,
                               float* __restrict__ out) {
    int idx = blockIdx.x * 256 + threadIdx.x;
    int t = idx / (DDIM / 8);
    int c = (idx % (DDIM / 8)) * 8;
    int s0 = tslot[2 * t], s1 = tslot[2 * t + 1];
    f16x8 a = *(const f16x8*)(y + (size_t)s0 * DDIM + c);
    f16x8 b = *(const f16x8*)(y + (size_t)s1 * DDIM + c);
    float4* o = (float4*)(out + (size_t)t * DDIM + c);
    float4 o0 = o[0], o1 = o[1];
    o0.x += (float)a[0] + (float)b[0];
    o0.y += (float)a[1] + (float)b[1];
    o0.z += (float)a[2] + (float)b[2];
    o0.w += (float)a[3] + (float)b[3];
    o1.x += (float)a[4] + (float)b[4];
    o1.y += (float)a[5] + (float)b[5];
    o1.z += (float)a[6] + (float)b[6];
    o1.w += (float)a[7] + (float)b[7];
    o[0] = o0; o[1] = o1;
}

// ---------------- MFMA GEMM, 128x128 tile, BK=64, 4 waves ----------------
// global_load_lds(16B) staging + XOR-swizzled LDS layout (no padding, conflict-free b128 reads)
#define FC1S 0
#define FC2S 1
#define FC1R 2
#define FC2R 3

template <int MODE>
__global__ __launch_bounds__(256, 2) void gemm_kernel(
    const _Float16* __restrict__ Abase,   // xh (fc1) or h (fc2), lda == K
    const _Float16* __restrict__ Wbase,   // [N,K] row-major (per expert for routed)
    const float* __restrict__ biasBase,
    _Float16* __restrict__ h,             // fc1 output; y scratch for FC2R
    float* __restrict__ out,              // fc2 shared output
    const int* __restrict__ cnt, const int* __restrict__ base,
    const int* __restrict__ rowsIdx, const float* __restrict__ rw)
{
    constexpr int K = (MODE == FC1S || MODE == FC1R) ? DDIM : FDIM;
    constexpr int N = (MODE == FC1S || MODE == FC1R) ? FDIM : DDIM;
    constexpr bool ROUTED = (MODE == FC1R || MODE == FC2R);

    int m0, mEnd;
    const _Float16* W;
    const float* bias;
    if constexpr (ROUTED) {
        int bx = blockIdx.x, accb = 0, expert = -1, rb = 0;
#pragma unroll
        for (int e = 0; e < E_EXP; e++) {
            int nb = (cnt[e] + 127) >> 7;
            if (expert < 0 && bx < accb + nb) { expert = e; rb = bx - accb; }
            accb += nb;
        }
        if (expert < 0) return;
        m0   = base[expert] + rb * 128;
        mEnd = base[expert] + cnt[expert];
        W    = Wbase + (size_t)expert * N * K;
        bias = biasBase + (size_t)expert * N;
    } else {
        m0 = blockIdx.x * 128;
        mEnd = T_TOK;
        W = Wbase;
        bias = biasBase;
    }
    int n0 = blockIdx.y * 128;

    // unpadded: row stride 64 f16 = 128B. Chunk (16B) at (row r, chunk c) stored at
    // position c ^ (r&7) -> ds_read_b128 spreads uniformly over all 32 banks.
    __shared__ __align__(16) _Float16 As[128 * 64];
    __shared__ __align__(16) _Float16 Bs[128 * 64];

    int tid  = threadIdx.x;
    int lane = tid & 63;
    int wid  = tid >> 6;
    int wm   = wid >> 1, wn = wid & 1;
    int m16  = lane & 15, q = lane >> 4;
    int x7   = m16 & 7;

    f32x4 acc[4][4];
#pragma unroll
    for (int i = 0; i < 4; i++)
#pragma unroll
        for (int j = 0; j < 4; j++) acc[i][j] = f32x4{0.f, 0.f, 0.f, 0.f};

    // per-thread staging source pointers (row + swizzled chunk folded in; bump by 64/iter)
    const _Float16* ap[4];
    const _Float16* bp[4];
#pragma unroll
    for (int tse = 0; tse < 4; tse++) {
        int L = wid * 256 + tse * 64 + lane;   // linear 16B-chunk index 0..1023
        int r = L >> 3;                        // tile row 0..127
        int c = (L & 7) ^ (r & 7);             // source chunk (XOR swizzle)
        int pr = m0 + r;
        bool valid = pr < mEnd;
        int ar;
        if constexpr (MODE == FC1R) ar = rowsIdx[valid ? pr : m0];
        else                        ar = valid ? pr : m0;
        ap[tse] = Abase + (size_t)ar * K + c * 8;
        bp[tse] = W + (size_t)(n0 + r) * K + c * 8;
    }

    for (int k0 = 0; k0 < K; k0 += 64) {
#pragma unroll
        for (int tse = 0; tse < 4; tse++) {
            // wave-uniform LDS base; lane's 16B lands at base + lane*16
            __builtin_amdgcn_global_load_lds(
                (const __attribute__((address_space(1))) void*)ap[tse],
                (__attribute__((address_space(3))) void*)(As + wid * 2048 + tse * 512),
                16, 0, 0);
            ap[tse] += 64;
        }
#pragma unroll
        for (int tse = 0; tse < 4; tse++) {
            __builtin_amdgcn_global_load_lds(
                (const __attribute__((address_space(1))) void*)bp[tse],
                (__attribute__((address_space(3))) void*)(Bs + wid * 2048 + tse * 512),
                16, 0, 0);
            bp[tse] += 64;
        }
        __syncthreads();
#pragma unroll
        for (int ks = 0; ks < 2; ks++) {
            f16x8 af[4], bf[4];
#pragma unroll
            for (int i = 0; i < 4; i++)
                af[i] = *(const f16x8*)(As + (wm * 64 + i * 16 + m16) * 64 + (((ks * 4 + q) ^ x7) * 8));
#pragma unroll
            for (int j = 0; j < 4; j++)
                bf[j] = *(const f16x8*)(Bs + (wn * 64 + j * 16 + m16) * 64 + (((ks * 4 + q) ^ x7) * 8));
#pragma unroll
            for (int i = 0; i < 4; i++)
#pragma unroll
                for (int j = 0; j < 4; j++)
                    acc[i][j] = __builtin_amdgcn_mfma_f32_16x16x32_f16(af[i], bf[j], acc[i][j], 0, 0, 0);
        }
        __syncthreads();
    }

    // epilogue. C/D layout: col = lane&15, row = (lane>>4)*4 + reg
    float biasv[4];
#pragma unroll
    for (int j = 0; j < 4; j++) biasv[j] = bias[n0 + wn * 64 + j * 16 + m16];

#pragma unroll
    for (int i = 0; i < 4; i++) {
#pragma unroll
        for (int r = 0; r < 4; r++) {
            int rowp = m0 + wm * 64 + i * 16 + q * 4 + r;
            if (rowp >= mEnd) continue;
            float wgt = 0.f;
            if constexpr (MODE == FC2R) wgt = rw[rowp];
#pragma unroll
            for (int j = 0; j < 4; j++) {
                int col = n0 + wn * 64 + j * 16 + m16;
                float v = acc[i][j][r] + biasv[j];
                if constexpr (MODE == FC1S || MODE == FC1R) {
                    v = 0.5f * v * (1.f + erff(v * 0.70710678118f));   // exact gelu
                    h[(size_t)rowp * FDIM + col] = (_Float16)v;
                } else if constexpr (MODE == FC2S) {
                    out[(size_t)rowp * DDIM + col] = v;                // rowp == token
                } else {                                               // FC2R: weighted f16 to y
                    h[(size_t)rowp * DDIM + col] = (_Float16)(v * wgt);
                }
            }
        }
    }
}

// ---------------- launch ----------------
extern "C" void kernel_launch(void* const* d_in, const int* in_sizes, int n_in,
                              void* d_out, int out_size, void* d_ws, size_t ws_size,
                              hipStream_t stream) {
    const float* x   = (const float*)d_in[0];
    const float* gw  = (const float*)d_in[1];
    const float* w1  = (const float*)d_in[2];
    const float* b1  = (const float*)d_in[3];
    const float* w2  = (const float*)d_in[4];
    const float* b2  = (const float*)d_in[5];
    const float* ws1 = (const float*)d_in[6];
    const float* bs1 = (const float*)d_in[7];
    const float* ws2 = (const float*)d_in[8];
    const float* bs2 = (const float*)d_in[9];
    float* out = (float*)d_out;
    char* ws = (char*)d_ws;
    if (ws_size < WS_NEED) return;   // fail loudly (output stays zero)

    _Float16* xh   = (_Float16*)(ws + XH_OFF);
    _Float16* w1h  = (_Float16*)(ws + W1H_OFF);
    _Float16* yb   = (_Float16*)(ws + Y_OFF);     // aliases w1h (dead after FC1R)
    _Float16* w2h  = (_Float16*)(ws + W2H_OFF);
    _Float16* ws1h = (_Float16*)(ws + WS1H_OFF);
    _Float16* ws2h = (_Float16*)(ws + WS2H_OFF);
    _Float16* h    = (_Float16*)(ws + H_OFF);
    int*   rowsIdx = (int*)(ws + ROWS_OFF);
    float* rw      = (float*)(ws + RW_OFF);
    int*   tidx    = (int*)(ws + TIDX_OFF);
    float* tw      = (float*)(ws + TW_OFF);
    int*   cnt     = (int*)(ws + CNT_OFF);
    int*   base    = (int*)(ws + BASE_OFF);
    int*   cur     = (int*)(ws + CUR_OFF);
    int*   tslot   = (int*)(ws + TSLOT_OFF);

    // conversions to fp16
    cvt_f32_f16<<<6144,  256, 0, stream>>>(x,   xh,   1572864);
    cvt_f32_f16<<<18432, 256, 0, stream>>>(w1,  w1h,  4718592);
    cvt_f32_f16<<<18432, 256, 0, stream>>>(w2,  w2h,  4718592);
    cvt_f32_f16<<<2304,  256, 0, stream>>>(ws1, ws1h, 589824);
    cvt_f32_f16<<<2304,  256, 0, stream>>>(ws2, ws2h, 589824);

    // routing (atomic-free count + low-contention scatter)
    gate_kernel<<<2048, 256, 0, stream>>>(x, gw, tidx, tw);
    count_kernel<<<1, 1024, 0, stream>>>(tidx, cnt, base, cur);
    scatter_kernel<<<32, 256, 0, stream>>>(tidx, tw, cur, rowsIdx, rw, tslot);

    // shared expert, then routed; FC2R writes weighted f16 into yb
    gemm_kernel<FC1S><<<dim3(64, 24),  256, 0, stream>>>(xh, ws1h, bs1, h, out, cnt, base, rowsIdx, rw);
    gemm_kernel<FC2S><<<dim3(64, 6),   256, 0, stream>>>(h,  ws2h, bs2, h, out, cnt, base, rowsIdx, rw);
    gemm_kernel<FC1R><<<dim3(136, 24), 256, 0, stream>>>(xh, w1h,  b1,  h, out, cnt, base, rowsIdx, rw);
    gemm_kernel<FC2R><<<dim3(136, 6),  256, 0, stream>>>(h,  w2h,  b2,  yb, out, cnt, base, rowsIdx, rw);

    // final combine: out[t] += y[slot0] + y[slot1]
    combine_kernel<<<3072, 256, 0, stream>>>(yb, tslot, out);
}

// Round 5
// 580.642 us; speedup vs baseline: 1.6452x; 1.0242x over previous
//
#include <hip/hip_runtime.h>
#include <hip/hip_bf16.h>

#define T_TOK 8192
#define E_EXP 8
#define DDIM  768
#define FDIM  3072

typedef _Float16 f16x8 __attribute__((ext_vector_type(8)));
typedef _Float16 f16x4 __attribute__((ext_vector_type(4)));
typedef float    f32x4 __attribute__((ext_vector_type(4)));

// ---------------- workspace layout (bytes, all 256-aligned) ----------------
static const size_t XH_OFF   = 0;                         // 8192*768*2   = 12,582,912
static const size_t W1H_OFF  = 12582912;                  // 8*3072*768*2 = 37,748,736
static const size_t Y_OFF    = W1H_OFF;                   // y[16384*768] f16 (reuses w1h region after FC1R)
static const size_t W2H_OFF  = 50331648;                  // 37,748,736
static const size_t WS1H_OFF = 88080384;                  // 4,718,592
static const size_t WS2H_OFF = 92798976;                  // 4,718,592
static const size_t H_OFF    = 97517568;                  // 16384*3072*2 = 100,663,296
static const size_t ROWS_OFF = 198180864;                 // 65,536
static const size_t RW_OFF   = 198246400;                 // 65,536
static const size_t TIDX_OFF = 198311936;                 // 65,536
static const size_t TW_OFF   = 198377472;                 // 65,536
static const size_t CNT_OFF  = 198443008;                 // 256
static const size_t BASE_OFF = 198443264;                 // 256
static const size_t CUR_OFF  = 198443520;                 // 256
static const size_t TSLOT_OFF= 198443776;                 // 65,536 (token -> 2 slots inverse map)
static const size_t WS_NEED  = 198509312;

// fast gelu: tanh-form via x*sigmoid(2z), z = 0.79788456*(x + 0.044715 x^3)
// ~8 VALU ops vs ~88 for __ocml_erf_f32 (R4 profile: 56us VALU-busy / 50M evals in FC1R).
// max dev vs exact-erf gelu ~3e-4; through fc2 (|w2|~0.02, 3072 terms) -> ~2e-4 on out.
__device__ inline float fast_gelu(float v) {
    float v2 = v * v;
    float z2n = v * __builtin_fmaf(v2, -0.0713548163f, -1.5957691216f);  // -2z
    float e = __expf(z2n);                                               // v_exp_f32
    float s = __builtin_amdgcn_rcpf(1.0f + e);                           // v_rcp_f32
    return v * s;   // +inf arg -> e=inf -> s=0 -> 0; -inf -> e=0 -> s=1 -> v
}

// ---------------- fp32 -> fp16 convert (vectorized) ----------------
__global__ void cvt_f32_f16(const float* __restrict__ src, _Float16* __restrict__ dst, int n4) {
    int i = blockIdx.x * blockDim.x + threadIdx.x;
    if (i >= n4) return;
    float4 v = ((const float4*)src)[i];
    f16x4 o = { (_Float16)v.x, (_Float16)v.y, (_Float16)v.z, (_Float16)v.w };
    *(f16x4*)(dst + 4 * (size_t)i) = o;
}

// ---------------- gate: fp32 logits, top-2, renormalized weights (no atomics) ----------------
__global__ void gate_kernel(const float* __restrict__ x, const float* __restrict__ gw,
                            int* __restrict__ tidx, float* __restrict__ tw) {
    int wave = threadIdx.x >> 6;
    int lane = threadIdx.x & 63;
    int t = blockIdx.x * 4 + wave;
    const float4* xv = (const float4*)(x + (size_t)t * DDIM);
    float p[E_EXP];
#pragma unroll
    for (int e = 0; e < E_EXP; e++) p[e] = 0.f;
    for (int i = lane; i < DDIM / 4; i += 64) {
        float4 xv4 = xv[i];
#pragma unroll
        for (int e = 0; e < E_EXP; e++) {
            float4 g = ((const float4*)(gw + (size_t)e * DDIM))[i];
            p[e] += xv4.x * g.x + xv4.y * g.y + xv4.z * g.z + xv4.w * g.w;
        }
    }
#pragma unroll
    for (int e = 0; e < E_EXP; e++) {
#pragma unroll
        for (int off = 32; off; off >>= 1) p[e] += __shfl_xor(p[e], off);
    }
    if (lane == 0) {
        int i0 = 0;
#pragma unroll
        for (int e = 1; e < E_EXP; e++) if (p[e] > p[i0]) i0 = e;
        int i1 = (i0 == 0) ? 1 : 0;
#pragma unroll
        for (int e = 0; e < E_EXP; e++) {
            if (e == i0) continue;
            if (p[e] > p[i1]) i1 = e;
        }
        float d  = p[i1] - p[i0];          // <= 0
        float e1 = expf(d);
        float w0 = 1.f / (1.f + e1);
        float w1 = 1.f - w0;
        tidx[2 * t]     = i0;  tw[2 * t]     = w0;
        tidx[2 * t + 1] = i1;  tw[2 * t + 1] = w1;
    }
}

// ---------------- count: single block, register histograms, zero atomics ----------------
__global__ void count_kernel(const int* __restrict__ tidx, int* __restrict__ cnt,
                             int* __restrict__ base, int* __restrict__ cur) {
    int c[E_EXP];
#pragma unroll
    for (int e = 0; e < E_EXP; e++) c[e] = 0;
    for (int i = threadIdx.x; i < 2 * T_TOK; i += 1024) {
        int e = tidx[i];
#pragma unroll
        for (int k = 0; k < E_EXP; k++) c[k] += (e == k) ? 1 : 0;
    }
#pragma unroll
    for (int e = 0; e < E_EXP; e++) {
#pragma unroll
        for (int off = 32; off; off >>= 1) c[e] += __shfl_xor(c[e], off);
    }
    __shared__ int wsum[16][E_EXP];
    int lane = threadIdx.x & 63, wave = threadIdx.x >> 6;
    if (lane == 0) {
#pragma unroll
        for (int e = 0; e < E_EXP; e++) wsum[wave][e] = c[e];
    }
    __syncthreads();
    if (threadIdx.x == 0) {
        int acc = 0;
        for (int e = 0; e < E_EXP; e++) {
            int s = 0;
            for (int w = 0; w < 16; w++) s += wsum[w][e];
            cnt[e] = s; base[e] = acc; cur[e] = acc; acc += s;
        }
    }
}

// ---------------- scatter: ballot ranking, 8 atomics per block; writes inverse map ----------------
__global__ void scatter_kernel(const int* __restrict__ tidx, const float* __restrict__ tw,
                               int* __restrict__ cur, int* __restrict__ rowsIdx,
                               float* __restrict__ rw, int* __restrict__ tslot) {
    int t = blockIdx.x * 256 + threadIdx.x;
    int lane = threadIdx.x & 63, wave = threadIdx.x >> 6;
    unsigned long long lt = ((unsigned long long)1 << lane) - 1ull;   // lanes below me
    __shared__ int wcnt[8][E_EXP];
    __shared__ int wpre[8][E_EXP];
    __shared__ int bbase[E_EXP];

    int myE[2], myR[2];
#pragma unroll
    for (int k = 0; k < 2; k++) {
        int e = tidx[2 * t + k];
        myE[k] = e;
        int vw = wave * 2 + k;
        int rank = 0;
#pragma unroll
        for (int ee = 0; ee < E_EXP; ee++) {
            unsigned long long m = __ballot(e == ee);
            if (e == ee) rank = __builtin_popcountll(m & lt);
            if (lane == 0) wcnt[vw][ee] = __builtin_popcountll(m);
        }
        myR[k] = rank;
    }
    __syncthreads();
    if (threadIdx.x < E_EXP) {
        int e = threadIdx.x, acc = 0;
#pragma unroll
        for (int vw = 0; vw < 8; vw++) { wpre[vw][e] = acc; acc += wcnt[vw][e]; }
        bbase[e] = atomicAdd(&cur[e], acc);
    }
    __syncthreads();
#pragma unroll
    for (int k = 0; k < 2; k++) {
        int e = myE[k];
        int slot = bbase[e] + wpre[wave * 2 + k][e] + myR[k];
        rowsIdx[slot] = t;
        rw[slot] = tw[2 * t + k];
        tslot[2 * t + k] = slot;
    }
}

// ---------------- combine: out[t] += y[s0] + y[s1]  (y already weighted) ----------------
__global__ void combine_kernel(const _Float16* __restrict__ y,
                               const int* __restrict__ tslot,
                               float* __restrict__ out) {
    int idx = blockIdx.x * 256 + threadIdx.x;
    int t = idx / (DDIM / 8);
    int c = (idx % (DDIM / 8)) * 8;
    int s0 = tslot[2 * t], s1 = tslot[2 * t + 1];
    f16x8 a = *(const f16x8*)(y + (size_t)s0 * DDIM + c);
    f16x8 b = *(const f16x8*)(y + (size_t)s1 * DDIM + c);
    float4* o = (float4*)(out + (size_t)t * DDIM + c);
    float4 o0 = o[0], o1 = o[1];
    o0.x += (float)a[0] + (float)b[0];
    o0.y += (float)a[1] + (float)b[1];
    o0.z += (float)a[2] + (float)b[2];
    o0.w += (float)a[3] + (float)b[3];
    o1.x += (float)a[4] + (float)b[4];
    o1.y += (float)a[5] + (float)b[5];
    o1.z += (float)a[6] + (float)b[6];
    o1.w += (float)a[7] + (float)b[7];
    o[0] = o0; o[1] = o1;
}

// ---------------- MFMA GEMM, 128x128 tile, BK=64, 4 waves ----------------
// global_load_lds(16B) staging + XOR-swizzled LDS layout (no padding, conflict-free b128 reads)
#define FC1S 0
#define FC2S 1
#define FC1R 2
#define FC2R 3

template <int MODE>
__global__ __launch_bounds__(256, 2) void gemm_kernel(
    const _Float16* __restrict__ Abase,   // xh (fc1) or h (fc2), lda == K
    const _Float16* __restrict__ Wbase,   // [N,K] row-major (per expert for routed)
    const float* __restrict__ biasBase,
    _Float16* __restrict__ h,             // fc1 output; y scratch for FC2R
    float* __restrict__ out,              // fc2 shared output
    const int* __restrict__ cnt, const int* __restrict__ base,
    const int* __restrict__ rowsIdx, const float* __restrict__ rw)
{
    constexpr int K = (MODE == FC1S || MODE == FC1R) ? DDIM : FDIM;
    constexpr int N = (MODE == FC1S || MODE == FC1R) ? FDIM : DDIM;
    constexpr bool ROUTED = (MODE == FC1R || MODE == FC2R);

    int m0, mEnd;
    const _Float16* W;
    const float* bias;
    if constexpr (ROUTED) {
        int bx = blockIdx.x, accb = 0, expert = -1, rb = 0;
#pragma unroll
        for (int e = 0; e < E_EXP; e++) {
            int nb = (cnt[e] + 127) >> 7;
            if (expert < 0 && bx < accb + nb) { expert = e; rb = bx - accb; }
            accb += nb;
        }
        if (expert < 0) return;
        m0   = base[expert] + rb * 128;
        mEnd = base[expert] + cnt[expert];
        W    = Wbase + (size_t)expert * N * K;
        bias = biasBase + (size_t)expert * N;
    } else {
        m0 = blockIdx.x * 128;
        mEnd = T_TOK;
        W = Wbase;
        bias = biasBase;
    }
    int n0 = blockIdx.y * 128;

    // unpadded: row stride 64 f16 = 128B. Chunk (16B) at (row r, chunk c) stored at
    // position c ^ (r&7) -> ds_read_b128 spreads uniformly over all 32 banks.
    __shared__ __align__(16) _Float16 As[128 * 64];
    __shared__ __align__(16) _Float16 Bs[128 * 64];

    int tid  = threadIdx.x;
    int lane = tid & 63;
    int wid  = tid >> 6;
    int wm   = wid >> 1, wn = wid & 1;
    int m16  = lane & 15, q = lane >> 4;
    int x7   = m16 & 7;

    f32x4 acc[4][4];
#pragma unroll
    for (int i = 0; i < 4; i++)
#pragma unroll
        for (int j = 0; j < 4; j++) acc[i][j] = f32x4{0.f, 0.f, 0.f, 0.f};

    // per-thread staging source pointers (row + swizzled chunk folded in; bump by 64/iter)
    const _Float16* ap[4];
    const _Float16* bp[4];
#pragma unroll
    for (int tse = 0; tse < 4; tse++) {
        int L = wid * 256 + tse * 64 + lane;   // linear 16B-chunk index 0..1023
        int r = L >> 3;                        // tile row 0..127
        int c = (L & 7) ^ (r & 7);             // source chunk (XOR swizzle)
        int pr = m0 + r;
        bool valid = pr < mEnd;
        int ar;
        if constexpr (MODE == FC1R) ar = rowsIdx[valid ? pr : m0];
        else                        ar = valid ? pr : m0;
        ap[tse] = Abase + (size_t)ar * K + c * 8;
        bp[tse] = W + (size_t)(n0 + r) * K + c * 8;
    }

    for (int k0 = 0; k0 < K; k0 += 64) {
#pragma unroll
        for (int tse = 0; tse < 4; tse++) {
            // wave-uniform LDS base; lane's 16B lands at base + lane*16
            __builtin_amdgcn_global_load_lds(
                (const __attribute__((address_space(1))) void*)ap[tse],
                (__attribute__((address_space(3))) void*)(As + wid * 2048 + tse * 512),
                16, 0, 0);
            ap[tse] += 64;
        }
#pragma unroll
        for (int tse = 0; tse < 4; tse++) {
            __builtin_amdgcn_global_load_lds(
                (const __attribute__((address_space(1))) void*)bp[tse],
                (__attribute__((address_space(3))) void*)(Bs + wid * 2048 + tse * 512),
                16, 0, 0);
            bp[tse] += 64;
        }
        __syncthreads();
#pragma unroll
        for (int ks = 0; ks < 2; ks++) {
            f16x8 af[4], bf[4];
#pragma unroll
            for (int i = 0; i < 4; i++)
                af[i] = *(const f16x8*)(As + (wm * 64 + i * 16 + m16) * 64 + (((ks * 4 + q) ^ x7) * 8));
#pragma unroll
            for (int j = 0; j < 4; j++)
                bf[j] = *(const f16x8*)(Bs + (wn * 64 + j * 16 + m16) * 64 + (((ks * 4 + q) ^ x7) * 8));
#pragma unroll
            for (int i = 0; i < 4; i++)
#pragma unroll
                for (int j = 0; j < 4; j++)
                    acc[i][j] = __builtin_amdgcn_mfma_f32_16x16x32_f16(af[i], bf[j], acc[i][j], 0, 0, 0);
        }
        __syncthreads();
    }

    // epilogue. C/D layout: col = lane&15, row = (lane>>4)*4 + reg
    float biasv[4];
#pragma unroll
    for (int j = 0; j < 4; j++) biasv[j] = bias[n0 + wn * 64 + j * 16 + m16];

#pragma unroll
    for (int i = 0; i < 4; i++) {
#pragma unroll
        for (int r = 0; r < 4; r++) {
            int rowp = m0 + wm * 64 + i * 16 + q * 4 + r;
            if (rowp >= mEnd) continue;
            float wgt = 0.f;
            if constexpr (MODE == FC2R) wgt = rw[rowp];
#pragma unroll
            for (int j = 0; j < 4; j++) {
                int col = n0 + wn * 64 + j * 16 + m16;
                float v = acc[i][j][r] + biasv[j];
                if constexpr (MODE == FC1S || MODE == FC1R) {
                    v = fast_gelu(v);
                    h[(size_t)rowp * FDIM + col] = (_Float16)v;
                } else if constexpr (MODE == FC2S) {
                    out[(size_t)rowp * DDIM + col] = v;                // rowp == token
                } else {                                               // FC2R: weighted f16 to y
                    h[(size_t)rowp * DDIM + col] = (_Float16)(v * wgt);
                }
            }
        }
    }
}

// ---------------- launch ----------------
extern "C" void kernel_launch(void* const* d_in, const int* in_sizes, int n_in,
                              void* d_out, int out_size, void* d_ws, size_t ws_size,
                              hipStream_t stream) {
    const float* x   = (const float*)d_in[0];
    const float* gw  = (const float*)d_in[1];
    const float* w1  = (const float*)d_in[2];
    const float* b1  = (const float*)d_in[3];
    const float* w2  = (const float*)d_in[4];
    const float* b2  = (const float*)d_in[5];
    const float* ws1 = (const float*)d_in[6];
    const float* bs1 = (const float*)d_in[7];
    const float* ws2 = (const float*)d_in[8];
    const float* bs2 = (const float*)d_in[9];
    float* out = (float*)d_out;
    char* ws = (char*)d_ws;
    if (ws_size < WS_NEED) return;   // fail loudly (output stays zero)

    _Float16* xh   = (_Float16*)(ws + XH_OFF);
    _Float16* w1h  = (_Float16*)(ws + W1H_OFF);
    _Float16* yb   = (_Float16*)(ws + Y_OFF);     // aliases w1h (dead after FC1R)
    _Float16* w2h  = (_Float16*)(ws + W2H_OFF);
    _Float16* ws1h = (_Float16*)(ws + WS1H_OFF);
    _Float16* ws2h = (_Float16*)(ws + WS2H_OFF);
    _Float16* h    = (_Float16*)(ws + H_OFF);
    int*   rowsIdx = (int*)(ws + ROWS_OFF);
    float* rw      = (float*)(ws + RW_OFF);
    int*   tidx    = (int*)(ws + TIDX_OFF);
    float* tw      = (float*)(ws + TW_OFF);
    int*   cnt     = (int*)(ws + CNT_OFF);
    int*   base    = (int*)(ws + BASE_OFF);
    int*   cur     = (int*)(ws + CUR_OFF);
    int*   tslot   = (int*)(ws + TSLOT_OFF);

    // conversions to fp16
    cvt_f32_f16<<<6144,  256, 0, stream>>>(x,   xh,   1572864);
    cvt_f32_f16<<<18432, 256, 0, stream>>>(w1,  w1h,  4718592);
    cvt_f32_f16<<<18432, 256, 0, stream>>>(w2,  w2h,  4718592);
    cvt_f32_f16<<<2304,  256, 0, stream>>>(ws1, ws1h, 589824);
    cvt_f32_f16<<<2304,  256, 0, stream>>>(ws2, ws2h, 589824);

    // routing (atomic-free count + low-contention scatter)
    gate_kernel<<<2048, 256, 0, stream>>>(x, gw, tidx, tw);
    count_kernel<<<1, 1024, 0, stream>>>(tidx, cnt, base, cur);
    scatter_kernel<<<32, 256, 0, stream>>>(tidx, tw, cur, rowsIdx, rw, tslot);

    // shared expert, then routed; FC2R writes weighted f16 into yb
    gemm_kernel<FC1S><<<dim3(64, 24),  256, 0, stream>>>(xh, ws1h, bs1, h, out, cnt, base, rowsIdx, rw);
    gemm_kernel<FC2S><<<dim3(64, 6),   256, 0, stream>>>(h,  ws2h, bs2, h, out, cnt, base, rowsIdx, rw);
    gemm_kernel<FC1R><<<dim3(136, 24), 256, 0, stream>>>(xh, w1h,  b1,  h, out, cnt, base, rowsIdx, rw);
    gemm_kernel<FC2R><<<dim3(136, 6),  256, 0, stream>>>(h,  w2h,  b2,  yb, out, cnt, base, rowsIdx, rw);

    // final combine: out[t] += y[slot0] + y[slot1]
    combine_kernel<<<3072, 256, 0, stream>>>(yb, tslot, out);
}